// Round 1
// baseline (75.405 us; speedup 1.0000x reference)
//
#include <hip/hip_runtime.h>
#include <hip/hip_bf16.h>
#include <math.h>

// GlobalConvolutionalLayer: out[b,i,m] = 0.5*xt_i * sum_l den[b,l]*gw[l]*exp(-xt_i*(g_l-g_m)^2)
// for i < CH(=15); channel CH is a raw copy of density.  xt_i = 1 + exp(-xi_i).
//
// Mercer/Taylor separation (grid in [0,1], xt <= 3.72 -> 2*xt*gl*gm <= 7.44):
//   exp(-xt (x-y)^2) = e^{-xt x^2} e^{-xt y^2} sum_n (2 xt)^n (x y)^n / n!
// With R=32 terms the truncation error is < 3e-8 relative; all terms >= 0 (stable).
//
// Phase A: per-channel constants (exp2 coefficient, scale, (2xt)^n/n!) + zero S.
// Phase B: moments S[i,n,b] = sum_l W[b,l] e^{-xt gl^2} gl^n  (shuffle-reduce + atomics).
// Phase C: out = 0.5 xt e^{-xt gm^2} * Horner_R(gm) with T[n] = cf[i,n]*S[i,n,b];
//          plus density copy for the last channel.

#define RTERMS 32
#define LOG2E 1.4426950408889634f

// ws float layout:
//   [0, CH*RTERMS*16)                : S[i][n][b]
//   aa = ws + CH*RTERMS*16, len CH   : -xt_i * log2(e)
//   sc = aa + CH, len CH             : 0.5 * xt_i
//   cf = sc + CH, len CH*RTERMS      : (2 xt_i)^n / n!

__global__ void gcl_phaseA(const float* __restrict__ xi, float* __restrict__ ws, int CH) {
    int t = threadIdx.x;
    int Ssz = CH * RTERMS * 16;
    float* aa = ws + Ssz;
    float* sc = aa + CH;
    float* cf = sc + CH;
    // zero the moment accumulators (d_ws is poisoned 0xAA before every launch)
    for (int j = t; j < Ssz; j += blockDim.x) ws[j] = 0.0f;
    if (t < CH) {
        float xt = 1.0f + __expf(-xi[t]);   // 1/sigmoid(x) = 1 + e^-x
        aa[t] = -xt * LOG2E;
        sc[t] = 0.5f * xt;
    }
    if (t < CH * RTERMS) {
        int i = t / RTERMS, n = t % RTERMS;
        float xt = 1.0f + __expf(-xi[i]);
        float z = 2.0f * xt;
        float p = 1.0f, f = 1.0f;
        for (int k = 1; k <= n; ++k) { p *= z; f *= (float)k; }
        cf[t] = p / f;
    }
}

// block: 256 threads; thread t -> b = t>>4 (0..15), s = t&15 (l sub-lane)
// grid: (CH, NCHUNK); block (i,c) covers l in [c*G/NCHUNK, (c+1)*G/NCHUNK)
__global__ void gcl_phaseB(const float* __restrict__ density, const float* __restrict__ grid,
                           const float* __restrict__ gw, float* __restrict__ ws,
                           int G, int CH) {
    int i = blockIdx.x;
    int c = blockIdx.y;
    int t = threadIdx.x;
    int b = t >> 4;
    int s = t & 15;
    const float* aa = ws + CH * RTERMS * 16;
    float a = aa[i];

    float acc[RTERMS];
#pragma unroll
    for (int n = 0; n < RTERMS; ++n) acc[n] = 0.0f;

    int chunk = G / gridDim.y;          // 256 for G=4096, NCHUNK=16
    int l0 = c * chunk;
    int iters = chunk >> 4;             // 16 l's per thread
    for (int it = 0; it < iters; ++it) {
        int l = l0 + it * 16 + s;       // consecutive s -> coalesced
        float gl = grid[l];
        float w = density[b * G + l] * gw[l] * exp2f(a * gl * gl);
        float p = w;
#pragma unroll
        for (int n = 0; n < RTERMS; ++n) { acc[n] += p; p *= gl; }
    }

    // reduce over the 16 s-lanes (contiguous lanes share b)
#pragma unroll
    for (int n = 0; n < RTERMS; ++n) {
        float v = acc[n];
        v += __shfl_xor(v, 1, 16);
        v += __shfl_xor(v, 2, 16);
        v += __shfl_xor(v, 4, 16);
        v += __shfl_xor(v, 8, 16);
        acc[n] = v;
    }
    if (s == 0) {
#pragma unroll
        for (int n = 0; n < RTERMS; ++n)
            atomicAdd(&ws[(i * RTERMS + n) * 16 + b], acc[n]);
    }
}

// grid: (G/256, CH+1, B); block 256 threads, one m per thread.
__global__ void gcl_phaseC(const float* __restrict__ density, const float* __restrict__ grid,
                           const float* __restrict__ ws, float* __restrict__ out,
                           int G, int CH) {
    int i = blockIdx.y;
    int b = blockIdx.z;
    int m = blockIdx.x * blockDim.x + threadIdx.x;
    int C = CH + 1;
    if (i == CH) {  // last channel: raw density copy (block-uniform branch)
        out[(b * C + i) * G + m] = density[b * G + m];
        return;
    }
    const float* aa = ws + CH * RTERMS * 16;
    const float* sc = aa + CH;
    const float* cf = sc + CH;

    __shared__ float T[RTERMS];
    if (threadIdx.x < RTERMS)
        T[threadIdx.x] = cf[i * RTERMS + threadIdx.x] * ws[(i * RTERMS + threadIdx.x) * 16 + b];
    __syncthreads();

    float gm = grid[m];
    float e = exp2f(aa[i] * gm * gm) * sc[i];
    float h = T[RTERMS - 1];
#pragma unroll
    for (int n = RTERMS - 2; n >= 0; --n) h = h * gm + T[n];
    out[(b * C + i) * G + m] = e * h;
}

extern "C" void kernel_launch(void* const* d_in, const int* in_sizes, int n_in,
                              void* d_out, int out_size, void* d_ws, size_t ws_size,
                              hipStream_t stream) {
    const float* density = (const float*)d_in[0];   // (B,1,G)
    const float* xi      = (const float*)d_in[1];   // (CH,)
    const float* grid    = (const float*)d_in[2];   // (G,)
    const float* gw      = (const float*)d_in[3];   // (G,)
    float* out = (float*)d_out;
    float* ws  = (float*)d_ws;

    int CH = in_sizes[1];          // 15
    int G  = in_sizes[2];          // 4096
    int B  = in_sizes[0] / G;      // 16

    gcl_phaseA<<<1, 512, 0, stream>>>(xi, ws, CH);
    gcl_phaseB<<<dim3(CH, 16), 256, 0, stream>>>(density, grid, gw, ws, G, CH);
    gcl_phaseC<<<dim3(G / 256, CH + 1, B), 256, 0, stream>>>(density, grid, ws, out, G, CH);
}

// Round 2
// 73.873 us; speedup vs baseline: 1.0207x; 1.0207x over previous
//
#include <hip/hip_runtime.h>
#include <hip/hip_bf16.h>
#include <math.h>

// GlobalConvolutionalLayer: out[b,i,m] = 0.5*xt_i * sum_l den[b,l]*gw[l]*exp(-xt_i*(g_l-g_m)^2)
// for i < CH(=15); channel CH is a raw density copy.  xt_i = 1 + exp(-xi_i) in (1.37, 3.72).
//
// Mercer/Taylor separation (grid in [0,1], 2*xt*gl*gm <= 7.44):
//   exp(-xt (x-y)^2) = e^{-xt x^2} e^{-xt y^2} sum_n (2 xt)^n (x y)^n / n!
// RTERMS=24 -> absolute tail error ~1e-2 (threshold 28.96); all terms >= 0 (stable).
//
// Kernel 1 (moments): per (channel i, chunk c) block computes partial moments
//   S[i,c,n,b] = sum_{l in chunk} den[b,l]*gw[l]*e^{-xt gl^2} gl^n
// written to private ws slots (no atomics, no ws pre-zero needed).
// Kernel 2 (eval): T[n,b] = (2xt)^n/n! * sum_c S[i,c,n,b]; out = 0.5 xt e^{-xt gm^2} Horner(gm).

#define RTERMS 24
#define NC 32
#define LOG2E 1.4426950408889634f

__global__ void gcl_moments(const float* __restrict__ density, const float* __restrict__ xi,
                            const float* __restrict__ grid, const float* __restrict__ gw,
                            float* __restrict__ ws, int G) {
    int i = blockIdx.x;
    int c = blockIdx.y;
    int t = threadIdx.x;
    int b = t >> 4;     // batch row 0..15
    int s = t & 15;     // l sub-lane
    float xt = 1.0f + __expf(-xi[i]);
    float a = -xt * LOG2E;

    float acc[RTERMS];
#pragma unroll
    for (int n = 0; n < RTERMS; ++n) acc[n] = 0.0f;

    int chunk = G / NC;            // 128 for G=4096
    int l0 = c * chunk;
    int iters = chunk >> 4;        // 8 l's per thread
    for (int it = 0; it < iters; ++it) {
        int l = l0 + it * 16 + s;  // consecutive s -> coalesced
        float gl = grid[l];
        float w = density[b * G + l] * gw[l] * exp2f(a * gl * gl);
        float gl2 = gl * gl;
        float gl4 = gl2 * gl2;
        // 4 independent power chains (dep depth RTERMS/4 instead of RTERMS)
        float p0 = w, p1 = w * gl, p2 = w * gl2, p3 = w * gl2 * gl;
#pragma unroll
        for (int k = 0; k < RTERMS / 4; ++k) {
            acc[4 * k + 0] += p0; p0 *= gl4;
            acc[4 * k + 1] += p1; p1 *= gl4;
            acc[4 * k + 2] += p2; p2 *= gl4;
            acc[4 * k + 3] += p3; p3 *= gl4;
        }
    }

    // reduce over the 16 s-lanes (contiguous lanes share b)
#pragma unroll
    for (int n = 0; n < RTERMS; ++n) {
        float v = acc[n];
        v += __shfl_xor(v, 1, 16);
        v += __shfl_xor(v, 2, 16);
        v += __shfl_xor(v, 4, 16);
        v += __shfl_xor(v, 8, 16);
        acc[n] = v;
    }
    if (s == 0) {
        float* base = ws + ((size_t)(i * NC + c) * RTERMS) * 16 + b;
#pragma unroll
        for (int n = 0; n < RTERMS; ++n) base[n * 16] = acc[n];
    }
}

// grid: (G/256, CH+1, B); block 256 threads, one m per thread.
__global__ void gcl_eval(const float* __restrict__ density, const float* __restrict__ xi,
                         const float* __restrict__ grid, const float* __restrict__ ws,
                         float* __restrict__ out, int G, int CH) {
    int i = blockIdx.y;
    int b = blockIdx.z;
    int m = blockIdx.x * blockDim.x + threadIdx.x;
    int C = CH + 1;
    if (i == CH) {  // raw density channel (block-uniform branch, before any barrier)
        out[((size_t)b * C + i) * G + m] = density[b * G + m];
        return;
    }
    float xt = 1.0f + __expf(-xi[i]);
    float a = -xt * LOG2E;

    __shared__ float T[RTERMS];
    if (threadIdx.x < RTERMS) {
        const float invfact[RTERMS] = {
            1.0f, 1.0f, 0.5f, 1.6666667e-1f, 4.1666667e-2f, 8.3333333e-3f,
            1.3888889e-3f, 1.9841270e-4f, 2.4801587e-5f, 2.7557319e-6f,
            2.7557319e-7f, 2.5052108e-8f, 2.0876757e-9f, 1.6059044e-10f,
            1.1470746e-11f, 7.6471637e-13f, 4.7794773e-14f, 2.8114573e-15f,
            1.5619207e-16f, 8.2206352e-18f, 4.1103176e-19f, 1.9572941e-20f,
            8.8967914e-22f, 3.8681702e-23f};
        int n = threadIdx.x;
        float cf = exp2f((float)n * __log2f(2.0f * xt)) * invfact[n];
        const float* p = ws + ((size_t)(i * NC) * RTERMS + n) * 16 + b;
        float ssum = 0.0f;
#pragma unroll
        for (int cc = 0; cc < NC; ++cc) ssum += p[(size_t)cc * RTERMS * 16];
        T[n] = cf * ssum;
    }
    __syncthreads();

    float gm = grid[m];
    float g2 = gm * gm;
    // even/odd split Horner: sum T[n] gm^n = He(g2) + gm*Ho(g2)
    float he = T[RTERMS - 2], ho = T[RTERMS - 1];
#pragma unroll
    for (int k = RTERMS - 4; k >= 0; k -= 2) {
        he = he * g2 + T[k];
        ho = ho * g2 + T[k + 1];
    }
    out[((size_t)b * C + i) * G + m] = exp2f(a * g2) * (0.5f * xt) * (he + gm * ho);
}

extern "C" void kernel_launch(void* const* d_in, const int* in_sizes, int n_in,
                              void* d_out, int out_size, void* d_ws, size_t ws_size,
                              hipStream_t stream) {
    const float* density = (const float*)d_in[0];   // (B,1,G) fp32
    const float* xi      = (const float*)d_in[1];   // (CH,)
    const float* grid    = (const float*)d_in[2];   // (G,)
    const float* gw      = (const float*)d_in[3];   // (G,)
    float* out = (float*)d_out;
    float* ws  = (float*)d_ws;

    int CH = in_sizes[1];          // 15
    int G  = in_sizes[2];          // 4096
    int B  = in_sizes[0] / G;      // 16

    gcl_moments<<<dim3(CH, NC), 256, 0, stream>>>(density, xi, grid, gw, ws, G);
    gcl_eval<<<dim3(G / 256, CH + 1, B), 256, 0, stream>>>(density, xi, grid, ws, out, G, CH);
}

// Round 3
// 71.180 us; speedup vs baseline: 1.0594x; 1.0378x over previous
//
#include <hip/hip_runtime.h>
#include <hip/hip_bf16.h>
#include <math.h>

// GlobalConvolutionalLayer, fully fused single kernel.
// out[b,i,m] = 0.5*xt_i * sum_l den[b,l]*gw[l]*exp(-xt_i*(g_l-g_m)^2), i < CH(=15)
// out[b,CH,m] = den[b,m].            xt_i = 1 + exp(-xi_i) in (1.37, 3.72).
//
// Mercer/Taylor separation (grid in [0,1], 2*xt*gl*gm <= 7.44):
//   exp(-xt (x-y)^2) = e^{-xt x^2} e^{-xt y^2} sum_n (2 xt)^n (x y)^n / n!
// RTERMS=24 -> absolute tail error ~1e-2 (vs threshold 28.96); all terms >= 0 (stable).
//
// One block per (i,b): compute moments S[n] = sum_l W e^{-xt gl^2} gl^n over all G,
// block-reduce, T[n] = (2xt)^n/n! * S[n], then evaluate the block's whole m-row:
//   out = 0.5 xt e^{-xt gm^2} * Horner_24(gm; T).
// No workspace, one launch. grid (CH+1, B) = 256 blocks = 1/CU.

#define RTERMS 24
#define LOG2E 1.4426950408889634f

__global__ __launch_bounds__(256) void gcl_fused(
        const float* __restrict__ density, const float* __restrict__ xi,
        const float* __restrict__ grid, const float* __restrict__ gw,
        float* __restrict__ out, int G, int CH) {
    int i = blockIdx.x;
    int b = blockIdx.y;
    int C = CH + 1;
    int t = threadIdx.x;

    if (i == CH) {  // raw density channel: vectorized row copy
        const float4* src = (const float4*)(density + (size_t)b * G);
        float4* dst = (float4*)(out + ((size_t)b * C + CH) * G);
        for (int j = t; j < G / 4; j += 256) dst[j] = src[j];
        return;
    }

    float xt = 1.0f + __expf(-xi[i]);
    float a = -xt * LOG2E;

    // ---- moments over all l ----
    float acc[RTERMS];
#pragma unroll
    for (int n = 0; n < RTERMS; ++n) acc[n] = 0.0f;

    const float* drow = density + (size_t)b * G;
    int iters = G >> 8;             // 16
    for (int it = 0; it < iters; ++it) {
        int l = (it << 8) + t;      // coalesced
        float gl = grid[l];
        float w = drow[l] * gw[l] * exp2f(a * gl * gl);
        float gl2 = gl * gl, gl4 = gl2 * gl2;
        float p0 = w, p1 = w * gl, p2 = w * gl2, p3 = p2 * gl;
#pragma unroll
        for (int k = 0; k < RTERMS / 4; ++k) {   // 4 chains: dep depth 6, not 24
            acc[4 * k + 0] += p0; p0 *= gl4;
            acc[4 * k + 1] += p1; p1 *= gl4;
            acc[4 * k + 2] += p2; p2 *= gl4;
            acc[4 * k + 3] += p3; p3 *= gl4;
        }
    }

    // ---- block reduction: wave shuffle, then LDS across 4 waves ----
#pragma unroll
    for (int n = 0; n < RTERMS; ++n) {
        float v = acc[n];
        v += __shfl_xor(v, 1);
        v += __shfl_xor(v, 2);
        v += __shfl_xor(v, 4);
        v += __shfl_xor(v, 8);
        v += __shfl_xor(v, 16);
        v += __shfl_xor(v, 32);
        acc[n] = v;
    }
    __shared__ float part[4][RTERMS];
    __shared__ float T[RTERMS];
    int wave = t >> 6, lane = t & 63;
    if (lane == 0) {
#pragma unroll
        for (int n = 0; n < RTERMS; ++n) part[wave][n] = acc[n];
    }
    __syncthreads();
    if (t < RTERMS) {
        const float invfact[RTERMS] = {
            1.0f, 1.0f, 0.5f, 1.6666667e-1f, 4.1666667e-2f, 8.3333333e-3f,
            1.3888889e-3f, 1.9841270e-4f, 2.4801587e-5f, 2.7557319e-6f,
            2.7557319e-7f, 2.5052108e-8f, 2.0876757e-9f, 1.6059044e-10f,
            1.1470746e-11f, 7.6471637e-13f, 4.7794773e-14f, 2.8114573e-15f,
            1.5619207e-16f, 8.2206352e-18f, 4.1103176e-19f, 1.9572941e-20f,
            8.8967914e-22f, 3.8681702e-23f};
        float s = part[0][t] + part[1][t] + part[2][t] + part[3][t];
        float cf = exp2f((float)t * __log2f(2.0f * xt)) * invfact[t];
        T[t] = s * cf;
    }
    __syncthreads();

    // ---- evaluate the row: T cached in registers, even/odd-split Horner ----
    float Tr[RTERMS];
#pragma unroll
    for (int n = 0; n < RTERMS; ++n) Tr[n] = T[n];

    float sc = 0.5f * xt;
    float* orow = out + ((size_t)b * C + i) * G;
    for (int it = 0; it < iters; ++it) {
        int m = (it << 8) + t;
        float gm = grid[m];
        float g2 = gm * gm;
        float he = Tr[RTERMS - 2], ho = Tr[RTERMS - 1];
#pragma unroll
        for (int k = RTERMS - 4; k >= 0; k -= 2) {
            he = he * g2 + Tr[k];
            ho = ho * g2 + Tr[k + 1];
        }
        orow[m] = exp2f(a * g2) * sc * (he + gm * ho);
    }
}

extern "C" void kernel_launch(void* const* d_in, const int* in_sizes, int n_in,
                              void* d_out, int out_size, void* d_ws, size_t ws_size,
                              hipStream_t stream) {
    const float* density = (const float*)d_in[0];   // (B,1,G) fp32
    const float* xi      = (const float*)d_in[1];   // (CH,)
    const float* grid    = (const float*)d_in[2];   // (G,)
    const float* gw      = (const float*)d_in[3];   // (G,)
    float* out = (float*)d_out;

    int CH = in_sizes[1];          // 15
    int G  = in_sizes[2];          // 4096
    int B  = in_sizes[0] / G;      // 16

    gcl_fused<<<dim3(CH + 1, B), 256, 0, stream>>>(density, xi, grid, gw, out, G, CH);
}